// Round 1
// baseline (77.035 us; speedup 1.0000x reference)
//
#include <hip/hip_runtime.h>

// TriangleScene: image-method specular path tracing validity check.
// T=2, R=4, P=1000, ORDER=2 (hard structural assumption: ORDER==2), NF=600.
// All float math uses __f*_rn intrinsics in the reference's evaluation order
// to avoid FMA contraction flipping borderline comparisons vs the numpy ref.

#define DEV __device__ __forceinline__

struct F3 { float x, y, z; };

DEV float fmul(float a, float b) { return __fmul_rn(a, b); }
DEV float fadd(float a, float b) { return __fadd_rn(a, b); }
DEV float fsub(float a, float b) { return __fsub_rn(a, b); }

DEV F3 f3sub(F3 a, F3 b) { return { fsub(a.x,b.x), fsub(a.y,b.y), fsub(a.z,b.z) }; }
// sum order matches np.sum over last axis: (x + y) + z
DEV float f3dot(F3 a, F3 b) {
  return fadd(fadd(fmul(a.x,b.x), fmul(a.y,b.y)), fmul(a.z,b.z));
}
DEV F3 f3cross(F3 a, F3 b) {
  return { fsub(fmul(a.y,b.z), fmul(a.z,b.y)),
           fsub(fmul(a.z,b.x), fmul(a.x,b.z)),
           fsub(fmul(a.x,b.y), fmul(a.y,b.x)) };
}

struct MTRes { float t; bool hit; };

// Moller-Trumbore, exactly mirroring _rays_intersect_triangles
DEV MTRes mt(F3 ro, F3 rd, F3 v0, F3 e1, F3 e2) {
  F3 h = f3cross(rd, e2);
  float a = f3dot(e1, h);
  bool conda = fabsf(a) < 1e-6f;
  float f = conda ? 0.0f : __fdiv_rn(1.0f, a);
  F3 s = f3sub(ro, v0);
  float u = fmul(f, f3dot(s, h));
  F3 q = f3cross(s, e1);
  float v = fmul(f, f3dot(rd, q));
  float tt = fmul(f, f3dot(e2, q));
  bool hit = (!conda) && (u >= 0.0f) && (u <= 1.0f) && (v >= 0.0f)
             && (fadd(u, v) <= 1.0f) && (tt > 1e-6f);
  return { tt, hit };
}

// Per-triangle record: 3 x float4 = {v0.xyz, e1.x}, {e1.yz, e2.xy}, {e2.z, n.xyz}
__global__ void k_pretri(const float* __restrict__ verts, const int* __restrict__ tris,
                         float4* __restrict__ out, int nf) {
  int f = blockIdx.x * blockDim.x + threadIdx.x;
  if (f >= nf) return;
  int i0 = tris[3*f+0], i1 = tris[3*f+1], i2 = tris[3*f+2];
  F3 v0 = { verts[3*i0], verts[3*i0+1], verts[3*i0+2] };
  F3 v1 = { verts[3*i1], verts[3*i1+1], verts[3*i1+2] };
  F3 v2 = { verts[3*i2], verts[3*i2+1], verts[3*i2+2] };
  F3 e1 = f3sub(v1, v0);
  F3 e2 = f3sub(v2, v0);
  F3 fn = f3cross(e1, e2);
  float nrm = __fsqrt_rn(fadd(fadd(fmul(fn.x,fn.x), fmul(fn.y,fn.y)), fmul(fn.z,fn.z)));
  F3 n = { __fdiv_rn(fn.x, nrm), __fdiv_rn(fn.y, nrm), __fdiv_rn(fn.z, nrm) };
  out[3*f+0] = make_float4(v0.x, v0.y, v0.z, e1.x);
  out[3*f+1] = make_float4(e1.y, e1.z, e2.x, e2.y);
  out[3*f+2] = make_float4(e2.z, n.x, n.y, n.z);
}

// One wave (64 lanes) per (t, r, p) path. Serial chain computed redundantly
// on all lanes (wave-uniform); occlusion test split over lanes, ballot-reduced.
__global__ __launch_bounds__(256) void k_paths(
    const float* __restrict__ txv, const float* __restrict__ rxv,
    const int* __restrict__ pc, const float4* __restrict__ tri,
    float* __restrict__ out, int T, int R, int P, int nf)
{
  const int lane = threadIdx.x & 63;
  const int pw = blockIdx.x * 4 + (threadIdx.x >> 6);   // wave id == path id
  const int nPaths = T * R * P;
  if (pw >= nPaths) return;
  const int p  = pw % P;
  const int tr = pw / P;
  const int r  = tr % R;
  const int t  = tr / R;

  const int f0 = pc[2*p + 0];
  const int f1 = pc[2*p + 1];
  float4 a0 = tri[3*f0], b0 = tri[3*f0+1], c0 = tri[3*f0+2];
  float4 a1 = tri[3*f1], b1 = tri[3*f1+1], c1 = tri[3*f1+2];
  F3 v00 = {a0.x,a0.y,a0.z}, e10 = {a0.w,b0.x,b0.y}, e20 = {b0.z,b0.w,c0.x}, n0 = {c0.y,c0.z,c0.w};
  F3 v01 = {a1.x,a1.y,a1.z}, e11 = {a1.w,b1.x,b1.y}, e21 = {b1.z,b1.w,c1.x}, n1 = {c1.y,c1.z,c1.w};

  F3 TX = { txv[3*t], txv[3*t+1], txv[3*t+2] };
  F3 RX = { rxv[3*r], rxv[3*r+1], rxv[3*r+2] };

  // forward scan: images. img = carry - (2*dot(carry-mv, mn)) * mn
  float d0  = f3dot(f3sub(TX, v00), n0);
  float td0 = fmul(2.0f, d0);
  F3 img1 = { fsub(TX.x, fmul(td0, n0.x)), fsub(TX.y, fmul(td0, n0.y)), fsub(TX.z, fmul(td0, n0.z)) };
  float d1  = f3dot(f3sub(img1, v01), n1);
  float td1 = fmul(2.0f, d1);
  F3 img2 = { fsub(img1.x, fmul(td1, n1.x)), fsub(img1.y, fmul(td1, n1.y)), fsub(img1.z, fmul(td1, n1.z)) };

  // backward scan (reverse): mirror1 first, then mirror0
  F3 u2 = f3sub(RX, img2);
  float un = f3dot(u2, n1);
  float vn = f3dot(f3sub(img2, v01), n1);
  float tb = (un == 0.0f) ? 0.0f : __fdiv_rn(-vn, un);
  F3 p1 = { fadd(img2.x, fmul(tb, u2.x)), fadd(img2.y, fmul(tb, u2.y)), fadd(img2.z, fmul(tb, u2.z)) };

  F3 u1 = f3sub(p1, img1);
  un = f3dot(u1, n0);
  vn = f3dot(f3sub(img1, v00), n0);
  tb = (un == 0.0f) ? 0.0f : __fdiv_rn(-vn, un);
  F3 p0 = { fadd(img1.x, fmul(tb, u1.x)), fadd(img1.y, fmul(tb, u1.y)), fadd(img1.z, fmul(tb, u1.z)) };

  // full_paths = [TX, p0, p1, RX]; rays = consecutive diffs
  F3 ro0 = TX, ro1 = p0, ro2 = p1;
  F3 rd0 = f3sub(p0, TX), rd1 = f3sub(p1, p0), rd2 = f3sub(RX, p1);

  // hit_in: ray i vs mirror triangle i (i = 0, 1)
  MTRes h0 = mt(ro0, rd0, v00, e10, e20);
  MTRes h1 = mt(ro1, rd1, v01, e11, e21);
  bool inside = h0.hit && h1.hit;

  // valid_refl: d_prev[i]*d_next[i] >= 0 for both mirrors
  float dp0 = f3dot(f3sub(TX, v00), n0);
  float dn0 = f3dot(f3sub(p1, v00), n0);
  float dp1 = f3dot(f3sub(p0, v01), n1);
  float dn1 = f3dot(f3sub(RX, v01), n1);
  bool vrefl = (fmul(dp0, dn0) >= 0.0f) && (fmul(dp1, dn1) >= 0.0f);

  // too_small: any segment shorter than MIN_LEN
  bool toosmall = (f3dot(rd0, rd0) < 1.2e-6f) ||
                  (f3dot(rd1, rd1) < 1.2e-6f) ||
                  (f3dot(rd2, rd2) < 1.2e-6f);

  // blocked: any of the 3 rays hits ANY triangle with t < 1 - HIT_TOL.
  // Skip entirely (wave-uniform) when the pre-mask already fails.
  bool pre = inside && vrefl && !toosmall;
  bool blocked = false;
  if (pre) {
    bool blk = false;
    for (int f = lane; f < nf; f += 64) {
      float4 aa = tri[3*f], bb = tri[3*f+1], cc = tri[3*f+2];
      F3 w0  = {aa.x, aa.y, aa.z};
      F3 we1 = {aa.w, bb.x, bb.y};
      F3 we2 = {bb.z, bb.w, cc.x};
      MTRes hb0 = mt(ro0, rd0, w0, we1, we2);
      MTRes hb1 = mt(ro1, rd1, w0, we1, we2);
      MTRes hb2 = mt(ro2, rd2, w0, we1, we2);
      blk = blk || (hb0.hit && (hb0.t < 0.999f))
                || (hb1.hit && (hb1.t < 0.999f))
                || (hb2.hit && (hb2.t < 0.999f));
    }
    blocked = (__ballot(blk) != 0ULL);
  }
  bool mask = pre && !blocked;

  if (lane == 0) {
    // full_paths: 12 floats per path, float4-aligned (pw*48 bytes)
    float4* fp = reinterpret_cast<float4*>(out) + (size_t)pw * 3;
    fp[0] = make_float4(TX.x, TX.y, TX.z, p0.x);
    fp[1] = make_float4(p0.y, p0.z, p1.x, p1.y);
    fp[2] = make_float4(p1.z, RX.x, RX.y, RX.z);
    // objects: [t, f0, f1, r] as floats
    float4* ob = reinterpret_cast<float4*>(out + (size_t)nPaths * 12) + pw;
    *ob = make_float4((float)t, (float)f0, (float)f1, (float)r);
    // mask
    out[(size_t)nPaths * 16 + pw] = mask ? 1.0f : 0.0f;
  }
}

extern "C" void kernel_launch(void* const* d_in, const int* in_sizes, int n_in,
                              void* d_out, int out_size, void* d_ws, size_t ws_size,
                              hipStream_t stream) {
  const float* mesh_v = (const float*)d_in[0];   // (NV,3) f32
  const int*   mesh_t = (const int*)d_in[1];     // (NF,3) i32
  const float* txv    = (const float*)d_in[2];   // (T,3)  f32
  const float* rxv    = (const float*)d_in[3];   // (R,3)  f32
  const int*   pc     = (const int*)d_in[4];     // (P,2)  i32

  const int NF = in_sizes[1] / 3;
  const int T  = in_sizes[2] / 3;
  const int R  = in_sizes[3] / 3;
  const int P  = in_sizes[4] / 2;   // ORDER == 2

  float4* tris = (float4*)d_ws;     // NF * 3 float4 = NF*48 bytes

  k_pretri<<<(NF + 255) / 256, 256, 0, stream>>>(mesh_v, mesh_t, tris, NF);

  const int nPaths = T * R * P;
  const int blocks = (nPaths + 3) / 4;            // 4 waves (paths) per block
  k_paths<<<blocks, 256, 0, stream>>>(txv, rxv, pc, tris, (float*)d_out,
                                      T, R, P, NF);
}